// Round 2
// baseline (1037.190 us; speedup 1.0000x reference)
//
#include <hip/hip_runtime.h>
#include <hip/hip_fp16.h>

// binary_dense on MI355X.
// out[b,o] = |gamma| * sum_{l,k} m[l,b,k] * sign(w[16l+c[l,b,k],k,o]) * mask[k,o]
// c = sign-pattern of (x, x[rm0], x[rm1], x[rm2]); m = |s0 s1 s2 s3|; exactly one
// of the 16 truth-table products survives per (l,b,k) and equals m.
//
// Round-2 structure:
//  zero_out -> pass_w (sign(w)*mask as 1-byte truncated-fp16) -> pass_mc ((m,c)
//  packed, c in low 4 mantissa bits) -> main_fma (grid 64 kslices x 8 btiles,
//  512 thr = 8 waves x 16 b x (64 lanes x 4 o); acc[16][4]=64 VGPRs; rows
//  staged to LDS as fp16 decoded via v_perm; atomicAdd partial k-slices into
//  out) -> scale_out (*|gamma|).
// ws: mc 64 MiB @0, sw 64 MiB @64MiB  (128 MiB total, same as round 1).

#define N_IN   8192
#define N_OUT  256
#define BATCH  1024
#define LEVELS 2

#define KSLICES 64
#define BTILES  8
#define BT      128

// ------------------------------------------------------------- zero / scale
__global__ __launch_bounds__(256) void zero_out(float* __restrict__ out) {
  out[blockIdx.x * 256 + threadIdx.x] = 0.f;
}

__global__ __launch_bounds__(256) void scale_out(float* __restrict__ out,
                                                 const float* __restrict__ gamma) {
  const int i = blockIdx.x * 256 + threadIdx.x;
  out[i] *= fabsf(gamma[0]);
}

// ------------------------------------------------- pass_w: sw = enc(sign(w)*mask)
// 1-byte code = top byte of fp16(sign(w)*mask): exact for 0 / +-1 (mask==1).
__global__ __launch_bounds__(256) void pass_w(const float* __restrict__ w,
                                              const float* __restrict__ mask,
                                              unsigned char* __restrict__ sw) {
  const size_t base = ((size_t)blockIdx.x * 256 + threadIdx.x) * 8;
  const size_t mo = base & (size_t)(N_IN * N_OUT - 1);
  float wv[8], mv[8];
  *(float4*)&wv[0] = *(const float4*)(w + base);
  *(float4*)&wv[4] = *(const float4*)(w + base + 4);
  *(float4*)&mv[0] = *(const float4*)(mask + mo);
  *(float4*)&mv[4] = *(const float4*)(mask + mo + 4);
  unsigned int u0 = 0, u1 = 0;
#pragma unroll
  for (int j = 0; j < 8; ++j) {
    const float v = (wv[j] > 0.f) ? mv[j] : ((wv[j] < 0.f) ? -mv[j] : 0.f);
    const unsigned int b = (unsigned int)(__half_as_ushort(__float2half(v)) >> 8);
    if (j < 4) u0 |= b << (j * 8); else u1 |= b << ((j - 4) * 8);
  }
  *(uint2*)(sw + base) = make_uint2(u0, u1);
}

// ---------------------------------------------------------------- pass_mc
__global__ __launch_bounds__(256) void pass_mc(const float* __restrict__ x,
                                               const int* __restrict__ rm0,
                                               const int* __restrict__ rm1,
                                               const int* __restrict__ rm2,
                                               unsigned int* __restrict__ mc) {
  __shared__ float xrow[N_IN];
  const int lb = blockIdx.x;                 // l*BATCH + b
  const size_t base = (size_t)lb * N_IN;
  const float4* xv = (const float4*)(x + base);
  const int t = threadIdx.x;
#pragma unroll
  for (int j = 0; j < 8; ++j) {
    float4 v = xv[t + j * 256];
    *(float4*)&xrow[4 * (t + j * 256)] = v;
  }
  __syncthreads();
#pragma unroll 4
  for (int j = 0; j < 32; ++j) {
    const int k = t + j * 256;
    const int r0 = rm0[k], r1 = rm1[k], r2 = rm2[k];
    const float s0 = xrow[k], s1 = xrow[r0], s2 = xrow[r1], s3 = xrow[r2];
    const float m = fabsf(s0 * s1 * s2 * s3);  // bitwise == reference product
    const unsigned c = ((s0 < 0.f) ? 8u : 0u) | ((s1 < 0.f) ? 4u : 0u) |
                       ((s2 < 0.f) ? 2u : 0u) | ((s3 < 0.f) ? 1u : 0u);
    mc[base + k] = (__float_as_uint(m) & ~0xFu) | c;   // c in low mantissa bits
  }
}

// ---------------------------------------------------------------- main pass
__global__ __launch_bounds__(512, 4) void main_fma(const unsigned char* __restrict__ sw,
                                                   const unsigned int* __restrict__ mc,
                                                   float* __restrict__ out) {
  __shared__ __half lw[4 * 16 * 256];                  // 4 k-units x 16 rows x 256 o, 32 KB
  __shared__ unsigned int lmc[16 * 128];               // 16 ku x 128 b, 8 KB

  const int ks = blockIdx.x;   // 0..63, 128 k each
  const int bt = blockIdx.y;   // 0..7, 128 b each
  const int t = threadIdx.x;
  const int lane = t & 63;
  const int wid = t >> 6;
  const int wb = wid * 16;     // wave's 16-b window in the tile

  float acc[16][4];
#pragma unroll
  for (int i = 0; i < 16; ++i) { acc[i][0] = acc[i][1] = acc[i][2] = acc[i][3] = 0.f; }

  // lw staging role: k-unit / row / 32-o segment (32 bytes of sw -> 32 halfs)
  const int s_kul = t >> 7;           // 0..3
  const int s_r   = (t >> 3) & 15;    // 0..15
  const int s_ob  = (t & 7) * 32;     // 0..224

  // lmc staging role: (l, b, 4-k half)
  const int g_l = t >> 8;             // 0..1
  const int g_b = (t >> 1) & 127;     // 0..127
  const int g_h = t & 1;              // 0..1

  for (int kc = 0; kc < 16; ++kc) {   // 8 k per chunk = 16 k-units (2 levels)
    const int k0 = ks * 128 + kc * 8;
    __syncthreads();                  // prev chunk's lmc/lw reads complete
    {
      const uint4 v = *(const uint4*)(mc + ((size_t)(g_l * BATCH + bt * BT + g_b) * N_IN + k0 + g_h * 4));
      unsigned int* dst = &lmc[(g_l * 8 + g_h * 4) * 128 + g_b];
      dst[0 * 128] = v.x; dst[1 * 128] = v.y; dst[2 * 128] = v.z; dst[3 * 128] = v.w;
    }
    __syncthreads();

    for (int sub = 0; sub < 4; ++sub) {     // 4 k-units per sub
      if (sub) __syncthreads();
      {
        const int ku = sub * 4 + s_kul;     // 0..15: l = ku>>3, kk = ku&7
        const int l = ku >> 3, kk = ku & 7;
        const unsigned char* src =
            sw + ((size_t)((l * 16 + s_r) * N_IN + (k0 + kk)) * N_OUT + s_ob);
        const uint4 a = ((const uint4*)src)[0];
        const uint4 b = ((const uint4*)src)[1];
        unsigned int dec[16];
        const unsigned int xs[8] = {a.x, a.y, a.z, a.w, b.x, b.y, b.z, b.w};
#pragma unroll
        for (int j = 0; j < 8; ++j) {
          // byte -> fp16 (<<8) pairs via v_perm; zeros pulled from s0==0
          dec[2 * j + 0] = __builtin_amdgcn_perm(0u, xs[j], 0x01040004u);
          dec[2 * j + 1] = __builtin_amdgcn_perm(0u, xs[j], 0x03040204u);
        }
        unsigned int* dst = (unsigned int*)&lw[(s_kul * 16 + s_r) * 256 + s_ob];
#pragma unroll
        for (int j = 0; j < 4; ++j) *(uint4*)(dst + 4 * j) = *(const uint4*)&dec[4 * j];
      }
      __syncthreads();

#pragma unroll
      for (int kul = 0; kul < 4; ++kul) {
        const int ku = sub * 4 + kul;
        const unsigned int* mrow = &lmc[ku * 128 + wb];
        const __half* wsel = lw + kul * 4096 + lane * 4;   // + c*256 per b
#pragma unroll
        for (int i = 0; i < 16; i += 4) {
          const uint4 q = *(const uint4*)(mrow + i);       // 4 b's (m,c), broadcast
#define DO_B(UQ, AI)                                                      \
  {                                                                       \
    const unsigned uq = (UQ);                                             \
    const float m = __uint_as_float(uq & 0xFFFFFFF0u);                    \
    union { uint2 u; __half h[4]; } wv_;                                  \
    wv_.u = *(const uint2*)(wsel + ((uq & 15u) << 8));                    \
    acc[AI][0] = fmaf(m, __half2float(wv_.h[0]), acc[AI][0]);             \
    acc[AI][1] = fmaf(m, __half2float(wv_.h[1]), acc[AI][1]);             \
    acc[AI][2] = fmaf(m, __half2float(wv_.h[2]), acc[AI][2]);             \
    acc[AI][3] = fmaf(m, __half2float(wv_.h[3]), acc[AI][3]);             \
  }
          DO_B(q.x, i + 0)
          DO_B(q.y, i + 1)
          DO_B(q.z, i + 2)
          DO_B(q.w, i + 3)
#undef DO_B
        }
      }
    }
  }

  // k-slice partial -> device-scope atomic accumulate (64 adders per output)
  float* dst0 = out + (size_t)(bt * BT + wb) * N_OUT + lane * 4;
#pragma unroll
  for (int i = 0; i < 16; ++i) {
    float* d = dst0 + (size_t)i * N_OUT;
    atomicAdd(d + 0, acc[i][0]);
    atomicAdd(d + 1, acc[i][1]);
    atomicAdd(d + 2, acc[i][2]);
    atomicAdd(d + 3, acc[i][3]);
  }
}

extern "C" void kernel_launch(void* const* d_in, const int* in_sizes, int n_in,
                              void* d_out, int out_size, void* d_ws, size_t ws_size,
                              hipStream_t stream) {
  const float* x     = (const float*)d_in[0];
  const float* w     = (const float*)d_in[1];
  const float* gamma = (const float*)d_in[2];
  const float* mask  = (const float*)d_in[3];
  const int* rm0     = (const int*)d_in[4];
  const int* rm1     = (const int*)d_in[5];
  const int* rm2     = (const int*)d_in[6];
  float* out = (float*)d_out;

  unsigned int* mc = (unsigned int*)d_ws;                                   // 64 MiB
  unsigned char* sw = (unsigned char*)d_ws + (size_t)LEVELS * BATCH * N_IN * 4; // 64 MiB
  (void)in_sizes; (void)n_in; (void)out_size; (void)ws_size;

  zero_out<<<dim3(BATCH), 256, 0, stream>>>(out);
  pass_w<<<dim3(32 * N_IN * N_OUT / (256 * 8)), 256, 0, stream>>>(w, mask, sw);
  pass_mc<<<dim3(LEVELS * BATCH), 256, 0, stream>>>(x, rm0, rm1, rm2, mc);
  main_fma<<<dim3(KSLICES, BTILES), 512, 0, stream>>>(sw, mc, out);
  scale_out<<<dim3(BATCH), 256, 0, stream>>>(out, gamma);
}